// Round 1
// baseline (41.771 us; speedup 1.0000x reference)
//
#include <hip/hip_runtime.h>

namespace {
constexpr int B_ = 32, S_ = 8, T_ = 128, D_ = 768, A_ = 8, L_ = 8;
constexpr int BS = B_ * S_;                       // 256
constexpr int MEAN_ELEMS = BS * D_;               // 196608
constexpr int EXT_ELEMS  = BS * A_ * D_;          // 1572864
constexpr int MEAN_BLOCKS = BS * (D_ / 2) / 256;  // 384 blocks of 256 thr, float2 each
constexpr int EXT_BLOCKS  = 3 * BS * A_;          // 6144

__global__ void __launch_bounds__(256) srl_kernel(
    const float* __restrict__ emb,
    const int* __restrict__ sids,
    const int* __restrict__ pred,
    const int* __restrict__ arg0,
    const int* __restrict__ arg1,
    float* __restrict__ out)
{
    const int blk = blockIdx.x;
    const int tid = threadIdx.x;

    if (blk < MEAN_BLOCKS) {
        // ---- mean over T: one float2 column per thread ----
        int idx = blk * 256 + tid;            // over BS * D/2
        int d2  = idx % (D_ / 2);
        int bs  = idx / (D_ / 2);
        const float2* p = reinterpret_cast<const float2*>(emb)
                          + (size_t)bs * T_ * (D_ / 2) + d2;
        float sx = 0.f, sy = 0.f;
        #pragma unroll 8
        for (int t = 0; t < T_; ++t) {
            float2 v = p[(size_t)t * (D_ / 2)];
            sx += v.x; sy += v.y;
        }
        float2 r; r.x = sx * (1.0f / T_); r.y = sy * (1.0f / T_);
        reinterpret_cast<float2*>(out)[(size_t)bs * (D_ / 2) + d2] = r;
        return;
    }

    // ---- extract: one block per (e, b, s, a) ----
    int eblk = blk - MEAN_BLOCKS;             // [0, 3*BS*A)
    int e    = eblk / (BS * A_);
    int rem  = eblk % (BS * A_);
    int bs   = rem / A_;
    int a    = rem % A_;
    const int* tokp = (e == 0 ? pred : (e == 1 ? arg0 : arg1))
                      + (size_t)(bs * A_ + a) * L_;

    __shared__ int toks[L_];
    __shared__ int pos[L_];
    if (tid < L_) { toks[tid] = tokp[tid]; pos[tid] = -1; }
    __syncthreads();
    if (tid < T_) {
        // cooperative inverse map: each of 128 threads checks its sentence id
        int id = sids[(size_t)bs * T_ + tid];
        #pragma unroll
        for (int l = 0; l < L_; ++l)
            if (toks[l] != 0 && id == toks[l]) pos[l] = tid;   // ids unique -> no race
    }
    __syncthreads();

    int n = 0;
    #pragma unroll
    for (int l = 0; l < L_; ++l) n += (toks[l] != 0);
    float inv = 1.0f / (float)(n < 1 ? 1 : n);

    const float* base = emb + (size_t)bs * T_ * D_;
    float a0 = 0.f, a1 = 0.f, a2 = 0.f;
    #pragma unroll
    for (int l = 0; l < L_; ++l) {
        int p = pos[l];
        if (p >= 0) {
            const float* row = base + (size_t)p * D_;
            a0 += row[tid];
            a1 += row[tid + 256];
            a2 += row[tid + 512];
        }
    }
    float* o = out + MEAN_ELEMS + (size_t)e * EXT_ELEMS + (size_t)(bs * A_ + a) * D_;
    o[tid]       = a0 * inv;
    o[tid + 256] = a1 * inv;
    o[tid + 512] = a2 * inv;
}
} // namespace

extern "C" void kernel_launch(void* const* d_in, const int* in_sizes, int n_in,
                              void* d_out, int out_size, void* d_ws, size_t ws_size,
                              hipStream_t stream) {
    const float* emb  = (const float*)d_in[0];
    const int*   sids = (const int*)d_in[1];
    const int*   pred = (const int*)d_in[2];
    const int*   arg0 = (const int*)d_in[3];
    const int*   arg1 = (const int*)d_in[4];
    float* out = (float*)d_out;

    dim3 grid(MEAN_BLOCKS + EXT_BLOCKS);
    srl_kernel<<<grid, 256, 0, stream>>>(emb, sids, pred, arg0, arg1, out);
}